// Round 1
// baseline (437.806 us; speedup 1.0000x reference)
//
#include <hip/hip_runtime.h>
#include <math.h>

#define DD 128
#define HH 32
#define MH 64
#define TT 256
#define ETA_C 1e-3f
#define BOUND_C 1.4907119849998598f   // sqrt(2/0.9)

// ws float layout:
//   F[32][128]   @ 0       (F[i][d] = (W_hist @ phi)[d,i])
//   P[32][128]   @ 4096    (p_i[n] = (M0[i] @ f_i)[n])
//   fn2[32]      @ 8192    (||f_i||^2)
//   s4[32]       @ 8224    (sigma_i^0.25)
//   m0n2[32]     @ 8256    (||M0[i]||_F^2)

__global__ void k_precompF(const float* __restrict__ W, const float* __restrict__ phi,
                           const float* __restrict__ sigma, float* __restrict__ ws) {
    int i = blockIdx.x, d = threadIdx.x;
    float acc = 0.f;
#pragma unroll
    for (int m = 0; m < MH; ++m) acc += W[d * MH + m] * phi[m * HH + i];
    ws[i * DD + d] = acc;
    __shared__ float red[DD];
    red[d] = acc * acc;
    __syncthreads();
    for (int o = 64; o > 0; o >>= 1) {
        if (d < o) red[d] += red[d + o];
        __syncthreads();
    }
    if (d == 0) {
        ws[8192 + i] = red[0];
        ws[8224 + i] = sqrtf(sqrtf(sigma[i]));
    }
}

__global__ void k_precompP(const float* __restrict__ M0, float* __restrict__ ws) {
    int i = blockIdx.x, n = threadIdx.x;
    const float* f  = ws + i * DD;
    const float* m0 = M0 + i * DD * DD + n * DD;
    float p = 0.f, sq = 0.f;
#pragma unroll 4
    for (int d = 0; d < DD; ++d) {
        float v = m0[d];
        p  += v * f[d];
        sq += v * v;
    }
    ws[4096 + i * DD + n] = p;
    __shared__ float red[DD];
    red[n] = sq;
    __syncthreads();
    for (int o = 64; o > 0; o >>= 1) {
        if (n < o) red[n] += red[n + o];
        __syncthreads();
    }
    if (n == 0) ws[8256 + i] = red[0];
}

// DPP cross-lane add (VALU pipe, not LDS). CTRL must be compile-time.
template <int CTRL>
__device__ __forceinline__ float dpp_add(float x) {
    int y = __builtin_amdgcn_update_dpp(0, __float_as_int(x), CTRL, 0xF, 0xF, true);
    return x + __int_as_float(y);
}
// 4-lane (quad) total: 0xB1 (xor1), 0x4E (xor2). 16-lane total: + 0x124 (ror:4), 0x128 (ror:8).

__launch_bounds__(512, 2)
__global__ void k_scan(const float* __restrict__ Am, const float* __restrict__ Bm,
                       const float* __restrict__ Qm, const float* __restrict__ Rm,
                       const float* __restrict__ Km, const float* __restrict__ x0,
                       const float* __restrict__ wseq, const float* __restrict__ ws,
                       float* __restrict__ out) {
    const int tid = threadIdx.x;
    const int r = tid >> 2, s = tid & 3, c0 = s << 5;

    // Register-resident matrices: thread owns row r, cols c0..c0+31.
    float mK[32], mQ[32], mA[32], mB[32], mR[32];
    {
        const float4* k4 = (const float4*)(Km + r * DD + c0);
        const float4* q4 = (const float4*)(Qm + r * DD + c0);
        const float4* a4 = (const float4*)(Am + r * DD + c0);
        const float4* b4 = (const float4*)(Bm + r * DD + c0);
        const float4* r4 = (const float4*)(Rm + r * DD + c0);
#pragma unroll
        for (int q = 0; q < 8; ++q) {
            float4 v;
            v = k4[q]; mK[4*q]=v.x; mK[4*q+1]=v.y; mK[4*q+2]=v.z; mK[4*q+3]=v.w;
            v = q4[q]; mQ[4*q]=v.x; mQ[4*q+1]=v.y; mQ[4*q+2]=v.z; mQ[4*q+3]=v.w;
            v = a4[q]; mA[4*q]=v.x; mA[4*q+1]=v.y; mA[4*q+2]=v.z; mA[4*q+3]=v.w;
            v = b4[q]; mB[4*q]=v.x; mB[4*q+1]=v.y; mB[4*q+2]=v.z; mB[4*q+3]=v.w;
            v = r4[q]; mR[4*q]=v.x; mR[4*q+1]=v.y; mR[4*q+2]=v.z; mR[4*q+3]=v.w;
        }
        // Rsym = R + R^T (one-time transposed reads)
#pragma unroll
        for (int j = 0; j < 32; ++j) mR[j] += Rm[(c0 + j) * DD + r];
    }

    // Per-filter owner state: filter oi, 16 threads/filter, 8 n's each.
    const int oi = tid >> 4, ol = tid & 15, on0 = ol << 3;
    float y[8], p[8];
    float oa, oe, ocy, os4, om0, ofn2;

    __shared__ float xs[2][DD];
    __shared__ float us[DD], gs[DD];
    __shared__ float Kx[DD], Qx[DD], Axv[DD], Buv[DD];
    __shared__ float Z[HH][132];   // noise partials z_i[n]; pad 132 (16B-aligned rows)
    __shared__ float qp[2], up[2];

    {
        os4  = ws[8224 + oi];
        ofn2 = ws[8192 + oi];
        om0  = ws[8256 + oi];
        oa = 1.f;
        oe = ETA_C * os4;
        ocy = os4 * ofn2;
#pragma unroll
        for (int j = 0; j < 8; ++j) {
            y[j] = 0.f;
            p[j] = ws[4096 + oi * DD + on0 + j];
        }
        float ca = os4 * oa;   // initial noise partials (M = 1*M0 + 0)
#pragma unroll
        for (int j = 0; j < 8; ++j) Z[oi][on0 + j] = ca * p[j];
    }
    if (tid < DD) xs[0][tid] = x0[tid];
    __syncthreads();

#pragma unroll 1
    for (int t = 0; t < TT; ++t) {
        const int cur = t & 1;
        // prefetch disturbance (used in phase 4)
        float wv = 0.f;
        if (tid < DD) wv = wseq[t * DD + tid];

        // ---- phase 1: Kx, Qx, Ax from xs[cur]
        {
            const float4* xv4 = (const float4*)(&xs[cur][0]) + (s << 3);
            float aK = 0.f, aQ = 0.f, aA = 0.f;
#pragma unroll
            for (int q = 0; q < 8; ++q) {
                float4 xv = xv4[q];
                aK += mK[4*q]*xv.x + mK[4*q+1]*xv.y + mK[4*q+2]*xv.z + mK[4*q+3]*xv.w;
                aQ += mQ[4*q]*xv.x + mQ[4*q+1]*xv.y + mQ[4*q+2]*xv.z + mQ[4*q+3]*xv.w;
                aA += mA[4*q]*xv.x + mA[4*q+1]*xv.y + mA[4*q+2]*xv.z + mA[4*q+3]*xv.w;
            }
            aK = dpp_add<0xB1>(aK); aK = dpp_add<0x4E>(aK);
            aQ = dpp_add<0xB1>(aQ); aQ = dpp_add<0x4E>(aQ);
            aA = dpp_add<0xB1>(aA); aA = dpp_add<0x4E>(aA);
            if (s == 0) { Kx[r] = aK; Qx[r] = aQ; Axv[r] = aA; }
            if (tid == 0 && t > 0)
                out[t - 1] = qp[0] + qp[1] + 0.5f * (up[0] + up[1]);
        }
        __syncthreads();

        // ---- phase 2: u = noise - Kx ; qpart = x.Qx
        if (tid < DD) {
            float a0 = -Kx[tid], a1 = 0.f;
#pragma unroll
            for (int i = 0; i < HH; i += 2) {  // conflict-free row reads
                a0 += Z[i][tid];
                a1 += Z[i + 1][tid];
            }
            us[tid] = a0 + a1;
        } else if (tid < 256) {
            int rr = tid & 127;
            float v = xs[cur][rr] * Qx[rr];
            v = dpp_add<0xB1>(v); v = dpp_add<0x4E>(v);
            v = dpp_add<0x124>(v); v = dpp_add<0x128>(v);
            v += __shfl_xor(v, 16); v += __shfl_xor(v, 32);
            if ((tid & 63) == 0) qp[(tid >> 6) & 1] = v;
        }
        __syncthreads();

        // ---- phase 3: g = Rsym u, Bu
        {
            const float4* uv4 = (const float4*)us + (s << 3);
            float aR = 0.f, aB = 0.f;
#pragma unroll
            for (int q = 0; q < 8; ++q) {
                float4 uv = uv4[q];
                aR += mR[4*q]*uv.x + mR[4*q+1]*uv.y + mR[4*q+2]*uv.z + mR[4*q+3]*uv.w;
                aB += mB[4*q]*uv.x + mB[4*q+1]*uv.y + mB[4*q+2]*uv.z + mB[4*q+3]*uv.w;
            }
            aR = dpp_add<0xB1>(aR); aR = dpp_add<0x4E>(aR);
            aB = dpp_add<0xB1>(aB); aB = dpp_add<0x4E>(aB);
            if (s == 0) { gs[r] = aR; Buv[r] = aB; }
        }
        __syncthreads();

        // ---- phase 4: x_next, upart = u.g, Y update + next noise partials
        if (tid < DD) {
            xs[cur ^ 1][tid] = Axv[tid] + Buv[tid] + wv;
        } else if (tid >= 256 && tid < 384) {
            int rr = tid & 127;
            float v = us[rr] * gs[rr];
            v = dpp_add<0xB1>(v); v = dpp_add<0x4E>(v);
            v = dpp_add<0x124>(v); v = dpp_add<0x128>(v);
            v += __shfl_xor(v, 16); v += __shfl_xor(v, 32);
            if ((tid & 63) == 0) up[(tid >> 6) & 1] = v;
        }
        {
            const float4* g4 = (const float4*)gs + (on0 >> 2);
            float4 ga = g4[0], gb = g4[1];
            float g8[8] = {ga.x, ga.y, ga.z, ga.w, gb.x, gb.y, gb.z, gb.w};
            float dyp = 0.f, dyy = 0.f;
#pragma unroll
            for (int j = 0; j < 8; ++j) {
                float yn = y[j] - oe * g8[j];
                y[j] = yn;
                dyp += yn * p[j];
                dyy += yn * yn;
            }
            dyp = dpp_add<0xB1>(dyp); dyp = dpp_add<0x4E>(dyp);
            dyp = dpp_add<0x124>(dyp); dyp = dpp_add<0x128>(dyp);
            dyy = dpp_add<0xB1>(dyy); dyy = dpp_add<0x4E>(dyy);
            dyy = dpp_add<0x124>(dyy); dyy = dpp_add<0x128>(dyy);
            // ||M_new[i]||^2 = a^2 ||M0||^2 + 2 a (y.p) + ||y||^2 ||f||^2
            float norm2 = oa * oa * om0 + 2.f * oa * dyp + ofn2 * dyy;
            float nrm = sqrtf(fmaxf(norm2, 0.f));
            float sc = (nrm > BOUND_C) ? (BOUND_C / nrm) : 1.f;
            oa *= sc;
            float ca = os4 * oa;
            float z8[8];
#pragma unroll
            for (int j = 0; j < 8; ++j) {
                y[j] *= sc;
                z8[j] = ca * p[j] + ocy * y[j];
            }
            float4* z4 = (float4*)(&Z[oi][on0]);
            z4[0] = make_float4(z8[0], z8[1], z8[2], z8[3]);
            z4[1] = make_float4(z8[4], z8[5], z8[6], z8[7]);
        }
        __syncthreads();
    }
    if (tid == 0) out[TT - 1] = qp[0] + qp[1] + 0.5f * (up[0] + up[1]);
}

extern "C" void kernel_launch(void* const* d_in, const int* in_sizes, int n_in,
                              void* d_out, int out_size, void* d_ws, size_t ws_size,
                              hipStream_t stream) {
    const float* A     = (const float*)d_in[0];
    const float* B     = (const float*)d_in[1];
    const float* Q     = (const float*)d_in[2];
    const float* R     = (const float*)d_in[3];
    const float* K     = (const float*)d_in[4];
    const float* sigma = (const float*)d_in[5];
    const float* phi   = (const float*)d_in[6];
    const float* M0    = (const float*)d_in[7];
    const float* x0    = (const float*)d_in[8];
    const float* Whist = (const float*)d_in[9];
    const float* wseq  = (const float*)d_in[10];
    float* out = (float*)d_out;
    float* ws  = (float*)d_ws;

    hipLaunchKernelGGL(k_precompF, dim3(HH), dim3(DD), 0, stream, Whist, phi, sigma, ws);
    hipLaunchKernelGGL(k_precompP, dim3(HH), dim3(DD), 0, stream, M0, ws);
    hipLaunchKernelGGL(k_scan, dim3(1), dim3(512), 0, stream,
                       A, B, Q, R, K, x0, wseq, ws, out);
}